// Round 4
// baseline (1176.448 us; speedup 1.0000x reference)
//
#include <hip/hip_runtime.h>
#include <hip/hip_bf16.h>

// GraphConvolution: x[B,N,D] fp32, W[K,D,O] fp32, COO edges per support (fp32 vals).
// out[b][n][k*O+o] = sum_{edges (r=n,c) in k} val * (x[b][c][:] @ W[k][:,o])
constexpr int B = 16, N = 10000, D = 128, O = 64, K = 3, E = 160000;
constexpr int BO = B * O;   // 1024
constexpr int KO = K * O;   // 192
constexpr int BSPL = 4;     // b-splits per 16-row n-tile (gemm grid = N/16 * BSPL)
constexpr int BPB  = B / BSPL;  // 4 b's per gemm block
constexpr int ROWS = 8;     // rows per spmm chunk
constexpr int NCH = N / ROWS;  // 1250
constexpr int SPMM_BLOCKS = 2048;  // 256 CU x 8 blocks (256 thr, <=64 VGPR): resident
constexpr int QBATCH = 4;          // chunks claimed per queue atomic

using short8  = __attribute__((ext_vector_type(8))) short;
using floatx4 = __attribute__((ext_vector_type(4))) float;
using f32x2   = __attribute__((ext_vector_type(2))) float;
struct U4 { unsigned a, b, c, d; };

__device__ __forceinline__ float bf2f(unsigned short u) {
  return __uint_as_float(((unsigned int)u) << 16);
}
// fp32 -> bf16, round-half-up (wpack only)
__device__ __forceinline__ unsigned short f2bf(float f) {
  return (unsigned short)((__float_as_uint(f) + 0x8000u) >> 16);
}
// packed fp32x2 -> bf16x2 (RNE), 1 VALU instead of 5
__device__ __forceinline__ unsigned cvtpk(float lo, float hi) {
  unsigned r;
  asm("v_cvt_pk_bf16_f32 %0, %1, %2" : "=v"(r) : "v"(lo), "v"(hi));
  return r;
}

// ---------------------------------------------------------------------------
// Kernel 0: repack W[K,D,O] fp32 -> MFMA A-fragment order (m=o, k=d), bf16.
// ---------------------------------------------------------------------------
__global__ void wpack_kernel(const float* __restrict__ w, unsigned short* __restrict__ wp) {
  const int i = blockIdx.x * 64 + threadIdx.x;
  if (i >= K * 16 * 64) return;
  const int lane = i & 63;
  const int dd = (i >> 6) & 3;
  const int t4 = (i >> 8) & 3;
  const int k  = i >> 10;
  const int o  = t4 * 16 + (lane & 15);
  const int d0 = dd * 32 + (lane >> 4) * 8;
  unsigned short* dst = wp + (size_t)i * 8;
#pragma unroll
  for (int j = 0; j < 8; ++j)
    dst[j] = f2bf(w[((size_t)k * D + d0 + j) * O + o]);
}

// ---------------------------------------------------------------------------
// Kernel 1: MFMA GEMM. pre[kloc][n][b*64+o] = sum_d x[b][n][d]*W[k][d][o] (bf16)
// A = W-frag (m=o), B = x-frag with n-axis = 16 CONSECUTIVE n (same b).
// ---------------------------------------------------------------------------
__global__ __launch_bounds__(192) void gemm_mfma_kernel(
    const float* __restrict__ x, const unsigned short* __restrict__ wpk,
    unsigned short* __restrict__ pre, int kBase)
{
  const int t = threadIdx.x;
  const int kloc = t >> 6;
  const int k = kBase + kloc;
  const int lane = t & 63;
  const int col  = lane & 15;   // n-axis of the B fragment
  const int quad = lane >> 4;

  short8 wfr[4][4];             // [t4][dd]
#pragma unroll
  for (int t4 = 0; t4 < 4; ++t4)
#pragma unroll
    for (int dd = 0; dd < 4; ++dd)
      wfr[t4][dd] = *(const short8*)(wpk + (size_t)(((k * 4 + t4) * 4 + dd) * 64 + lane) * 8);

  const int n0 = (blockIdx.x / BSPL) * 16;
  const int b0 = (blockIdx.x % BSPL) * BPB;
  const int n  = n0 + col;

  for (int bb = 0; bb < BPB; ++bb) {
    const int b = b0 + bb;
    const float* xp = x + ((size_t)b * N + n) * D + quad * 8;
    short8 xfr[4];
#pragma unroll
    for (int dd = 0; dd < 4; ++dd) {
      const float4 lo = *(const float4*)(xp + dd * 32);
      const float4 hi = *(const float4*)(xp + dd * 32 + 4);
      U4 u;
      u.a = cvtpk(lo.x, lo.y); u.b = cvtpk(lo.z, lo.w);
      u.c = cvtpk(hi.x, hi.y); u.d = cvtpk(hi.z, hi.w);
      xfr[dd] = __builtin_bit_cast(short8, u);
    }

    floatx4 acc[4] = {};
#pragma unroll
    for (int dd = 0; dd < 4; ++dd)
#pragma unroll
      for (int t4 = 0; t4 < 4; ++t4)
        acc[t4] = __builtin_amdgcn_mfma_f32_16x16x32_bf16(wfr[t4][dd], xfr[dd], acc[t4], 0, 0, 0);

    // D layout: col(lane&15)=n-axis, row(quad*4+j)=o-axis
    unsigned short* pp = pre + (((size_t)kloc * N + n) << 10) + b * 64 + quad * 4;
#pragma unroll
    for (int t4 = 0; t4 < 4; ++t4) {
      uint2 pk2;
      pk2.x = cvtpk(acc[t4][0], acc[t4][1]);
      pk2.y = cvtpk(acc[t4][2], acc[t4][3]);
      *(uint2*)(pp + t4 * 16) = pk2;
    }
  }
}

// ---------------------------------------------------------------------------
// Kernel 2: per-row edge histogram
// ---------------------------------------------------------------------------
__global__ void hist_kernel(const int* __restrict__ row, int* __restrict__ cnt) {
  const int i = blockIdx.x * 256 + threadIdx.x;
  if (i >= K * E) return;
  const int k = i / E;
  atomicAdd(&cnt[k * N + row[i]], 1);
}

// ---------------------------------------------------------------------------
// Kernel 3: exclusive scan per support -> CSR offsets (cnt becomes cursor)
// ---------------------------------------------------------------------------
__global__ __launch_bounds__(1024) void scan_kernel(int* __restrict__ cnt,
                                                    int* __restrict__ offs) {
  const int k = blockIdx.x;
  const int t = threadIdx.x;
  const int lane = t & 63, wid = t >> 6;
  __shared__ int wt[16];
  __shared__ int sbase;
  if (t == 0) { sbase = 0; offs[k * (N + 1)] = 0; }
  __syncthreads();

  for (int c0 = 0; c0 < N; c0 += 1024) {
    const int i = c0 + t;
    const int v = (i < N) ? cnt[k * N + i] : 0;
    int incl = v;
#pragma unroll
    for (int st = 1; st < 64; st <<= 1) {
      const int u = __shfl_up(incl, st, 64);
      if (lane >= st) incl += u;
    }
    if (lane == 63) wt[wid] = incl;
    __syncthreads();
    if (wid == 0) {
      int wv = (lane < 16) ? wt[lane] : 0;
#pragma unroll
      for (int st = 1; st < 16; st <<= 1) {
        const int u = __shfl_up(wv, st, 64);
        if (lane >= st) wv += u;
      }
      if (lane < 16) wt[lane] = wv;
    }
    __syncthreads();
    const int base = sbase + ((wid > 0) ? wt[wid - 1] : 0);
    if (i < N) {
      offs[k * (N + 1) + i + 1] = base + incl;
      cnt[k * N + i] = base + incl - v;
    }
    __syncthreads();
    if (t == 0) sbase += wt[15];
    __syncthreads();
  }
}

// ---------------------------------------------------------------------------
// Kernel 4: scatter edges into CSR order
// ---------------------------------------------------------------------------
__global__ void scatter_kernel(const int* __restrict__ row, const int* __restrict__ col,
                               const float* __restrict__ vals,
                               int* __restrict__ cursor, int* __restrict__ scol,
                               float* __restrict__ sval) {
  const int i = blockIdx.x * 256 + threadIdx.x;
  if (i >= K * E) return;
  const int k = i / E;
  const int pos = atomicAdd(&cursor[k * N + row[i]], 1);
  scol[k * E + pos] = col[i];
  sval[k * E + pos] = vals[i];
}

// ---------------------------------------------------------------------------
// Kernel 5: CSR SpMM, TRUE XCD pinning via HW_REG_XCC_ID + per-XCD work queue.
// Each XCD self-selects bo-group g = XCC_ID and pulls (k,nc) chunks k-major
// from queue qcnt[kBase*8+g] in batches of QBATCH. Live pre footprint per XCD
// = one k-slice of its 256B bo-stripe = 2.56 MB < 4 MB L2 -> gathers hit L2.
// Fallback: after own queue drains, probe all others (load-guarded), so
// correctness never depends on XCC_ID (worst case = unpinned).
// Termination: queue counter is monotone, every claim advances it; no
// barriers in-kernel -> no deadlock. Stale cross-XCD loads only under-read
// the counter -> at worst one extra atomic, never a hang.
// ---------------------------------------------------------------------------
__global__ __launch_bounds__(256, 8) void spmm_kernel(
    const unsigned short* __restrict__ pre, const int* __restrict__ offs,
    const int* __restrict__ scol, const float* __restrict__ sval,
    float* __restrict__ out, int* __restrict__ qcnt, int kBase, int kCount)
{
  int gx;
  asm volatile("s_getreg_b32 %0, hwreg(HW_REG_XCC_ID)" : "=s"(gx));
  const int lane = threadIdx.x & 63;
  const int total = kCount * NCH;

  for (int gg = 0; gg < 8; ++gg) {
    const int g = (gx + gg) & 7;
    int* q = qcnt + (kBase * 8 + g);
    if (gg && *(volatile const int*)q >= total) continue;  // cheap drained check

    const int bo = g * 128 + 2 * lane;  // 2 consecutive bo per lane
    const int b = bo >> 6;
    const int o = bo & 63;

    for (;;) {
      int c0 = 0;
      if (lane == 0) c0 = atomicAdd(q, QBATCH);
      int c = __shfl(c0, 0, 64);
      if (c >= total) break;
      const int cend = (c + QBATCH < total) ? c + QBATCH : total;

      for (; c < cend; ++c) {
        const int kloc = c / NCH;
        const int nc   = c - kloc * NCH;
        const int k = kBase + kloc;

        const unsigned short* pk = pre + (((size_t)kloc * N) << 10) + bo;
        const int* cj = scol + (size_t)k * E;
        const float* vj = sval + (size_t)k * E;
        const int* op = offs + k * (N + 1) + nc * ROWS;

        for (int r = 0; r < ROWS; ++r) {
          const int j0 = __builtin_amdgcn_readfirstlane(op[r]);
          const int j1 = __builtin_amdgcn_readfirstlane(op[r + 1]);
          float a0 = 0.f, a1 = 0.f;
          int j = j0;
          for (; j + 7 < j1; j += 8) {
            unsigned u[8]; float v[8];
#pragma unroll
            for (int i = 0; i < 8; ++i) {
              const int c2 = __builtin_amdgcn_readfirstlane(cj[j + i]);  // SGPR base
              u[i] = *(const unsigned*)(pk + ((size_t)c2 << 10));
              v[i] = __builtin_nontemporal_load(vj + j + i);  // edge stream: no L2 alloc
            }
#pragma unroll
            for (int i = 0; i < 8; ++i) {
              a0 += v[i] * bf2f((unsigned short)(u[i] & 0xFFFFu));
              a1 += v[i] * bf2f((unsigned short)(u[i] >> 16));
            }
          }
          for (; j < j1; ++j) {
            const int c2 = __builtin_amdgcn_readfirstlane(cj[j]);
            const float v = __builtin_nontemporal_load(vj + j);
            const unsigned u = *(const unsigned*)(pk + ((size_t)c2 << 10));
            a0 += v * bf2f((unsigned short)(u & 0xFFFFu));
            a1 += v * bf2f((unsigned short)(u >> 16));
          }
          const int n = nc * ROWS + r;
          f32x2 st; st.x = a0; st.y = a1;
          // write-only stream: nt store keeps L2 for pre
          __builtin_nontemporal_store(st,
              (f32x2*)(out + ((size_t)b * N + n) * KO + (size_t)k * O + o));
        }
      }
    }
  }
}

// ---------------------------------------------------------------------------
extern "C" void kernel_launch(void* const* d_in, const int* in_sizes, int n_in,
                              void* d_out, int out_size, void* d_ws, size_t ws_size,
                              hipStream_t stream) {
  const float* x    = (const float*)d_in[0];
  const float* w    = (const float*)d_in[1];
  const float* vals = (const float*)d_in[2];
  const int* row    = (const int*)d_in[3];
  const int* col    = (const int*)d_in[4];
  float* out        = (float*)d_out;

  char* p = (char*)d_ws;
  int* qcnt = (int*)p;            p += 128;   // 24 counters (K * 8 groups)
  int* offs = (int*)p;            p += ((size_t)K * (N + 1) * 4 + 15) & ~(size_t)15;
  int* cnt  = (int*)p;            p += (size_t)K * N * 4;
  int* scol = (int*)p;            p += (size_t)K * E * 4;
  float* sval = (float*)p;        p += (size_t)K * E * 4;
  unsigned short* wpk = (unsigned short*)p; p += (size_t)K * 16 * 64 * 8 * 2;
  unsigned short* pre = (unsigned short*)p;
  const size_t fixed = (size_t)(p - (char*)d_ws);
  const size_t preFull = (size_t)K * N * BO * 2;
  const bool full = ws_size >= fixed + preFull;  // ws_size constant across calls

  hipMemsetAsync(qcnt, 0, 128, stream);
  hipMemsetAsync(cnt, 0, (size_t)K * N * 4, stream);

  wpack_kernel<<<48, 64, 0, stream>>>(w, wpk);
  const int eb = (K * E + 255) / 256;
  hist_kernel<<<eb, 256, 0, stream>>>(row, cnt);
  scan_kernel<<<K, 1024, 0, stream>>>(cnt, offs);
  scatter_kernel<<<eb, 256, 0, stream>>>(row, col, vals, cnt, scol, sval);

  if (full) {
    gemm_mfma_kernel<<<(N / 16) * BSPL, 64 * K, 0, stream>>>(x, wpk, pre, 0);
    spmm_kernel<<<SPMM_BLOCKS, 256, 0, stream>>>(pre, offs, scol, sval, out, qcnt, 0, K);
  } else {
    for (int k = 0; k < K; ++k) {
      gemm_mfma_kernel<<<(N / 16) * BSPL, 64, 0, stream>>>(x, wpk, pre, k);
      spmm_kernel<<<SPMM_BLOCKS, 256, 0, stream>>>(pre, offs, scol, sval, out, qcnt, k, 1);
    }
  }
  (void)in_sizes; (void)n_in; (void)out_size;
}

// Round 5
// 395.038 us; speedup vs baseline: 2.9781x; 2.9781x over previous
//
#include <hip/hip_runtime.h>
#include <hip/hip_bf16.h>

// GraphConvolution: x[B,N,D] fp32, W[K,D,O] fp32, COO edges per support (fp32 vals).
// out[b][n][k*O+o] = sum_{edges (r=n,c) in k} val * (x[b][c][:] @ W[k][:,o])
constexpr int B = 16, N = 10000, D = 128, O = 64, K = 3, E = 160000;
constexpr int BO = B * O;   // 1024
constexpr int KO = K * O;   // 192
constexpr int BSPL = 4;     // b-splits per 16-row n-tile (gemm grid = N/16 * BSPL)
constexpr int BPB  = B / BSPL;  // 4 b's per gemm block
constexpr int G = 8;        // spmm bo-groups
constexpr int ROWS = 8;     // rows per spmm block
constexpr int NCH = N / ROWS;  // 1250

using short8  = __attribute__((ext_vector_type(8))) short;
using floatx4 = __attribute__((ext_vector_type(4))) float;
using f32x2   = __attribute__((ext_vector_type(2))) float;
struct U4 { unsigned a, b, c, d; };

__device__ __forceinline__ float bf2f(unsigned short u) {
  return __uint_as_float(((unsigned int)u) << 16);
}
// fp32 -> bf16, round-half-up (wpack only)
__device__ __forceinline__ unsigned short f2bf(float f) {
  return (unsigned short)((__float_as_uint(f) + 0x8000u) >> 16);
}
// packed fp32x2 -> bf16x2 (RNE), 1 VALU instead of 5
__device__ __forceinline__ unsigned cvtpk(float lo, float hi) {
  unsigned r;
  asm("v_cvt_pk_bf16_f32 %0, %1, %2" : "=v"(r) : "v"(lo), "v"(hi));
  return r;
}

// ---------------------------------------------------------------------------
// Kernel 0: repack W[K,D,O] fp32 -> MFMA A-fragment order (m=o, k=d), bf16.
// ---------------------------------------------------------------------------
__global__ void wpack_kernel(const float* __restrict__ w, unsigned short* __restrict__ wp) {
  const int i = blockIdx.x * 64 + threadIdx.x;
  if (i >= K * 16 * 64) return;
  const int lane = i & 63;
  const int dd = (i >> 6) & 3;
  const int t4 = (i >> 8) & 3;
  const int k  = i >> 10;
  const int o  = t4 * 16 + (lane & 15);
  const int d0 = dd * 32 + (lane >> 4) * 8;
  unsigned short* dst = wp + (size_t)i * 8;
#pragma unroll
  for (int j = 0; j < 8; ++j)
    dst[j] = f2bf(w[((size_t)k * D + d0 + j) * O + o]);
}

// ---------------------------------------------------------------------------
// Kernel 1: MFMA GEMM. pre[kloc][n][b*64+o] = sum_d x[b][n][d]*W[k][d][o] (bf16)
// A = W-frag (m=o), B = x-frag with n-axis = 16 CONSECUTIVE n (same b):
// per load inst, 4 quads cover 64B contiguous per row -> full HBM granules.
// ---------------------------------------------------------------------------
__global__ __launch_bounds__(192) void gemm_mfma_kernel(
    const float* __restrict__ x, const unsigned short* __restrict__ wpk,
    unsigned short* __restrict__ pre, int kBase)
{
  const int t = threadIdx.x;
  const int kloc = t >> 6;
  const int k = kBase + kloc;
  const int lane = t & 63;
  const int col  = lane & 15;   // n-axis of the B fragment
  const int quad = lane >> 4;

  short8 wfr[4][4];             // [t4][dd]
#pragma unroll
  for (int t4 = 0; t4 < 4; ++t4)
#pragma unroll
    for (int dd = 0; dd < 4; ++dd)
      wfr[t4][dd] = *(const short8*)(wpk + (size_t)(((k * 4 + t4) * 4 + dd) * 64 + lane) * 8);

  const int n0 = (blockIdx.x / BSPL) * 16;
  const int b0 = (blockIdx.x % BSPL) * BPB;
  const int n  = n0 + col;

  for (int bb = 0; bb < BPB; ++bb) {
    const int b = b0 + bb;
    const float* xp = x + ((size_t)b * N + n) * D + quad * 8;
    short8 xfr[4];
#pragma unroll
    for (int dd = 0; dd < 4; ++dd) {
      const float4 lo = *(const float4*)(xp + dd * 32);
      const float4 hi = *(const float4*)(xp + dd * 32 + 4);
      U4 u;
      u.a = cvtpk(lo.x, lo.y); u.b = cvtpk(lo.z, lo.w);
      u.c = cvtpk(hi.x, hi.y); u.d = cvtpk(hi.z, hi.w);
      xfr[dd] = __builtin_bit_cast(short8, u);
    }

    floatx4 acc[4] = {};
#pragma unroll
    for (int dd = 0; dd < 4; ++dd)
#pragma unroll
      for (int t4 = 0; t4 < 4; ++t4)
        acc[t4] = __builtin_amdgcn_mfma_f32_16x16x32_bf16(wfr[t4][dd], xfr[dd], acc[t4], 0, 0, 0);

    // D layout: col(lane&15)=n-axis, row(quad*4+j)=o-axis
    unsigned short* pp = pre + (((size_t)kloc * N + n) << 10) + b * 64 + quad * 4;
#pragma unroll
    for (int t4 = 0; t4 < 4; ++t4) {
      uint2 pk2;
      pk2.x = cvtpk(acc[t4][0], acc[t4][1]);
      pk2.y = cvtpk(acc[t4][2], acc[t4][3]);
      *(uint2*)(pp + t4 * 16) = pk2;
    }
  }
}

// ---------------------------------------------------------------------------
// Kernel 2: per-row edge histogram
// ---------------------------------------------------------------------------
__global__ void hist_kernel(const int* __restrict__ row, int* __restrict__ cnt) {
  const int i = blockIdx.x * 256 + threadIdx.x;
  if (i >= K * E) return;
  const int k = i / E;
  atomicAdd(&cnt[k * N + row[i]], 1);
}

// ---------------------------------------------------------------------------
// Kernel 3: exclusive scan per support -> CSR offsets (cnt becomes cursor)
// ---------------------------------------------------------------------------
__global__ __launch_bounds__(1024) void scan_kernel(int* __restrict__ cnt,
                                                    int* __restrict__ offs) {
  const int k = blockIdx.x;
  const int t = threadIdx.x;
  const int lane = t & 63, wid = t >> 6;
  __shared__ int wt[16];
  __shared__ int sbase;
  if (t == 0) { sbase = 0; offs[k * (N + 1)] = 0; }
  __syncthreads();

  for (int c0 = 0; c0 < N; c0 += 1024) {
    const int i = c0 + t;
    const int v = (i < N) ? cnt[k * N + i] : 0;
    int incl = v;
#pragma unroll
    for (int st = 1; st < 64; st <<= 1) {
      const int u = __shfl_up(incl, st, 64);
      if (lane >= st) incl += u;
    }
    if (lane == 63) wt[wid] = incl;
    __syncthreads();
    if (wid == 0) {
      int wv = (lane < 16) ? wt[lane] : 0;
#pragma unroll
      for (int st = 1; st < 16; st <<= 1) {
        const int u = __shfl_up(wv, st, 64);
        if (lane >= st) wv += u;
      }
      if (lane < 16) wt[lane] = wv;
    }
    __syncthreads();
    const int base = sbase + ((wid > 0) ? wt[wid - 1] : 0);
    if (i < N) {
      offs[k * (N + 1) + i + 1] = base + incl;
      cnt[k * N + i] = base + incl - v;
    }
    __syncthreads();
    if (t == 0) sbase += wt[15];
    __syncthreads();
  }
}

// ---------------------------------------------------------------------------
// Kernel 4: scatter edges into CSR order
// ---------------------------------------------------------------------------
__global__ void scatter_kernel(const int* __restrict__ row, const int* __restrict__ col,
                               const float* __restrict__ vals,
                               int* __restrict__ cursor, int* __restrict__ scol,
                               float* __restrict__ sval) {
  const int i = blockIdx.x * 256 + threadIdx.x;
  if (i >= K * E) return;
  const int k = i / E;
  const int pos = atomicAdd(&cursor[k * N + row[i]], 1);
  scol[k * E + pos] = col[i];
  sval[k * E + pos] = vals[i];
}

// ---------------------------------------------------------------------------
// Kernel 5: CSR SpMM — round-0 proven structure (static 1-wave blocks, k-major
// block order, g=bid&7) + 16-deep gather unroll for 2x memory-level
// parallelism (the round-0 version was latency-bound at 44% HBM BW with only
// 8 gathers in flight behind a serial cj->gather chain). Plain loads for
// edge data (L2-cached; nt-load was the round-4 disaster). nt store for out.
// ---------------------------------------------------------------------------
__global__ __launch_bounds__(64) void spmm_kernel(
    const unsigned short* __restrict__ pre, const int* __restrict__ offs,
    const int* __restrict__ scol, const float* __restrict__ sval,
    float* __restrict__ out, int kBase)
{
  const int bid = blockIdx.x;
  const int g   = bid & 7;
  const int t2  = bid >> 3;
  const int nc  = t2 % NCH;
  const int kloc = t2 / NCH;            // k-major: all nc for k before k+1
  const int k = kBase + kloc;
  const int lane = threadIdx.x;

  const int bo = g * 128 + 2 * lane;    // 2 consecutive bo per lane
  const int b = bo >> 6;
  const int o = bo & 63;
  const unsigned short* pk = pre + (((size_t)kloc * N) << 10) + bo;
  const int* cj = scol + (size_t)k * E;
  const float* vj = sval + (size_t)k * E;
  const int* op = offs + k * (N + 1) + nc * ROWS;

  int ofs[ROWS + 1];
#pragma unroll
  for (int r = 0; r <= ROWS; ++r) ofs[r] = __builtin_amdgcn_readfirstlane(op[r]);

  for (int r = 0; r < ROWS; ++r) {
    const int j0 = ofs[r];
    const int j1 = ofs[r + 1];
    float a0 = 0.f, a1 = 0.f;
    int j = j0;
    // 16 gathers in flight
    for (; j + 15 < j1; j += 16) {
      unsigned u[16]; float v[16];
#pragma unroll
      for (int i = 0; i < 16; ++i) {
        const int c2 = __builtin_amdgcn_readfirstlane(cj[j + i]);  // SGPR base
        u[i] = *(const unsigned*)(pk + ((size_t)c2 << 10));
        v[i] = vj[j + i];
      }
#pragma unroll
      for (int i = 0; i < 16; ++i) {
        a0 += v[i] * bf2f((unsigned short)(u[i] & 0xFFFFu));
        a1 += v[i] * bf2f((unsigned short)(u[i] >> 16));
      }
    }
    for (; j + 7 < j1; j += 8) {
      unsigned u[8]; float v[8];
#pragma unroll
      for (int i = 0; i < 8; ++i) {
        const int c2 = __builtin_amdgcn_readfirstlane(cj[j + i]);
        u[i] = *(const unsigned*)(pk + ((size_t)c2 << 10));
        v[i] = vj[j + i];
      }
#pragma unroll
      for (int i = 0; i < 8; ++i) {
        a0 += v[i] * bf2f((unsigned short)(u[i] & 0xFFFFu));
        a1 += v[i] * bf2f((unsigned short)(u[i] >> 16));
      }
    }
    for (; j < j1; ++j) {
      const int c2 = __builtin_amdgcn_readfirstlane(cj[j]);
      const float v = vj[j];
      const unsigned u = *(const unsigned*)(pk + ((size_t)c2 << 10));
      a0 += v * bf2f((unsigned short)(u & 0xFFFFu));
      a1 += v * bf2f((unsigned short)(u >> 16));
    }
    const int n = nc * ROWS + r;
    f32x2 st; st.x = a0; st.y = a1;
    // write-only stream: nt store keeps L2 for pre
    __builtin_nontemporal_store(st,
        (f32x2*)(out + ((size_t)b * N + n) * KO + (size_t)k * O + o));
  }
}

// ---------------------------------------------------------------------------
extern "C" void kernel_launch(void* const* d_in, const int* in_sizes, int n_in,
                              void* d_out, int out_size, void* d_ws, size_t ws_size,
                              hipStream_t stream) {
  const float* x    = (const float*)d_in[0];
  const float* w    = (const float*)d_in[1];
  const float* vals = (const float*)d_in[2];
  const int* row    = (const int*)d_in[3];
  const int* col    = (const int*)d_in[4];
  float* out        = (float*)d_out;

  char* p = (char*)d_ws;
  int* offs = (int*)p;            p += ((size_t)K * (N + 1) * 4 + 15) & ~(size_t)15;
  int* cnt  = (int*)p;            p += (size_t)K * N * 4;
  int* scol = (int*)p;            p += (size_t)K * E * 4;
  float* sval = (float*)p;        p += (size_t)K * E * 4;
  unsigned short* wpk = (unsigned short*)p; p += (size_t)K * 16 * 64 * 8 * 2;
  unsigned short* pre = (unsigned short*)p;
  const size_t fixed = (size_t)(p - (char*)d_ws);
  const size_t preFull = (size_t)K * N * BO * 2;
  const bool full = ws_size >= fixed + preFull;  // ws_size constant across calls

  hipMemsetAsync(cnt, 0, (size_t)K * N * 4, stream);

  wpack_kernel<<<48, 64, 0, stream>>>(w, wpk);
  const int eb = (K * E + 255) / 256;
  hist_kernel<<<eb, 256, 0, stream>>>(row, cnt);
  scan_kernel<<<K, 1024, 0, stream>>>(cnt, offs);
  scatter_kernel<<<eb, 256, 0, stream>>>(row, col, vals, cnt, scol, sval);

  if (full) {
    gemm_mfma_kernel<<<(N / 16) * BSPL, 64 * K, 0, stream>>>(x, wpk, pre, 0);
    spmm_kernel<<<K * NCH * G, 64, 0, stream>>>(pre, offs, scol, sval, out, 0);
  } else {
    for (int k = 0; k < K; ++k) {
      gemm_mfma_kernel<<<(N / 16) * BSPL, 64, 0, stream>>>(x, wpk, pre, k);
      spmm_kernel<<<NCH * G, 64, 0, stream>>>(pre, offs, scol, sval, out, k);
    }
  }
  (void)in_sizes; (void)n_in; (void)out_size;
}